// Round 3
// baseline (299.167 us; speedup 1.0000x reference)
//
#include <hip/hip_runtime.h>
#include <hip/hip_bf16.h>
#include <cstdint>

#define NH 12
#define DH 64
#define TSEQ 4096
#define BATCH 2
#define CDIM 768
#define MROWS (BATCH*TSEQ)

typedef __bf16 bf16x8 __attribute__((ext_vector_type(8)));
typedef bf16x8 bf16x8_a __attribute__((may_alias));
typedef float f32x4 __attribute__((ext_vector_type(4)));

__device__ __forceinline__ uint16_t f2bu(float f) {
  uint32_t u = __float_as_uint(f);
  u += 0x7fffu + ((u >> 16) & 1u);
  return (uint16_t)(u >> 16);
}

__device__ __forceinline__ void gload_lds16(const void* g, void* l) {
  __builtin_amdgcn_global_load_lds(
      (const __attribute__((address_space(1))) void*)g,
      (__attribute__((address_space(3))) void*)l, 16, 0, 0);
}

// ---------------- cast fp32 -> bf16 (vectorized) ----------------
__global__ void cast_f32_bf16(const float* __restrict__ in, uint16_t* __restrict__ out, int n4) {
  int i = blockIdx.x * blockDim.x + threadIdx.x;
  int stride = gridDim.x * blockDim.x;
  for (; i < n4; i += stride) {
    float4 v = ((const float4*)in)[i];
    ushort4 o;
    o.x = f2bu(v.x); o.y = f2bu(v.y); o.z = f2bu(v.z); o.w = f2bu(v.w);
    ((ushort4*)out)[i] = o;
  }
}

// ---------------- transpose + cast: W[K][N] f32 -> Wt[N][K] bf16 ----------------
__global__ void transpose_cast(const float* __restrict__ w, uint16_t* __restrict__ wt, int K, int N) {
  __shared__ float tile[32][33];
  int kb = blockIdx.x * 32, nb = blockIdx.y * 32;
  int tx = threadIdx.x & 31, ty = threadIdx.x >> 5;
  #pragma unroll
  for (int r = ty; r < 32; r += 8) tile[r][tx] = w[(size_t)(kb + r) * N + nb + tx];
  __syncthreads();
  #pragma unroll
  for (int r = ty; r < 32; r += 8) wt[(size_t)(nb + r) * K + kb + tx] = f2bu(tile[tx][r]);
}

// ---------------- GEMM: C[M,N] = A[M,K](bf16) @ Bt[N,K]^T(bf16) + bias ----------------
// MODE 0: scatter Q (pre-scaled by 0.125*log2e) and K into [B,H,T,Dh]; V into V^T [B,H,Dh,T].
// MODE 1: write fp32 to outf [M,N].
template <int MODE>
__global__ __launch_bounds__(256) void gemm_bt(
    const uint16_t* __restrict__ A, const uint16_t* __restrict__ Bt,
    const float* __restrict__ bias,
    uint16_t* __restrict__ q, uint16_t* __restrict__ k, uint16_t* __restrict__ v,
    float* __restrict__ outf, int N, int K) {
  __shared__ uint16_t As[128 * 32];
  __shared__ uint16_t Bs[128 * 32];
  int tid = threadIdx.x;
  int w = tid >> 6, l = tid & 63;
  int lg = l >> 4, lr = l & 15;
  int mb = blockIdx.x * 128, nb = blockIdx.y * 128;
  int wr = (w >> 1) * 64, wc = (w & 1) * 64;
  f32x4 acc[4][4] = {};
  int srow = tid >> 2, scol = (tid & 3) * 8;
  const uint16_t* Ag = A + (size_t)(mb + srow) * K + scol;
  const uint16_t* Bg = Bt + (size_t)(nb + srow) * K + scol;
  char* AsB = (char*)As + (size_t)w * 1024;
  char* BsB = (char*)Bs + (size_t)w * 1024;
  size_t rowskip = (size_t)64 * K;
  for (int kb = 0; kb < K; kb += 32) {
    __syncthreads();
    gload_lds16(Ag + kb, AsB);
    gload_lds16(Ag + kb + rowskip, AsB + 4096);
    gload_lds16(Bg + kb, BsB);
    gload_lds16(Bg + kb + rowskip, BsB + 4096);
    __syncthreads();
    bf16x8 af[4], bfr[4];
    #pragma unroll
    for (int i = 0; i < 4; ++i)
      af[i] = *(const bf16x8_a*)(const void*)(As + (wr + i * 16 + lr) * 32 + lg * 8);
    #pragma unroll
    for (int i = 0; i < 4; ++i)
      bfr[i] = *(const bf16x8_a*)(const void*)(Bs + (wc + i * 16 + lr) * 32 + lg * 8);
    #pragma unroll
    for (int mi = 0; mi < 4; ++mi)
      #pragma unroll
      for (int ni = 0; ni < 4; ++ni)
        acc[mi][ni] = __builtin_amdgcn_mfma_f32_16x16x32_bf16(af[mi], bfr[ni], acc[mi][ni], 0, 0, 0);
  }
  #pragma unroll
  for (int mi = 0; mi < 4; ++mi) {
    #pragma unroll
    for (int ni = 0; ni < 4; ++ni) {
      if (MODE == 0) {
        int gm0 = mb + wr + mi * 16 + lg * 4;
        int gn = nb + wc + ni * 16 + lr;
        int which = gn / CDIM;
        int cc = gn - which * CDIM;
        int hh = cc >> 6, d = cc & 63;
        float bs = bias[gn];
        if (which == 2) {
          int b0 = gm0 >> 12, t0 = gm0 & 4095;
          ushort4 pk;
          pk.x = f2bu(acc[mi][ni][0] + bs);
          pk.y = f2bu(acc[mi][ni][1] + bs);
          pk.z = f2bu(acc[mi][ni][2] + bs);
          pk.w = f2bu(acc[mi][ni][3] + bs);
          *(ushort4*)&v[(((size_t)(b0 * NH + hh)) * DH + d) * TSEQ + t0] = pk;
        } else {
          uint16_t* dst = which ? k : q;
          float sc = which ? 1.0f : 0.1803368801111204f;  // 0.125 * log2(e)
          #pragma unroll
          for (int j = 0; j < 4; ++j) {
            int gm = gm0 + j;
            int bb = gm >> 12, t = gm & 4095;
            float val = (acc[mi][ni][j] + bs) * sc;
            dst[(((size_t)(bb * NH + hh)) * TSEQ + t) * DH + d] = f2bu(val);
          }
        }
      } else {
        #pragma unroll
        for (int j = 0; j < 4; ++j) {
          int gm = mb + wr + mi * 16 + lg * 4 + j;
          int gn = nb + wc + ni * 16 + lr;
          outf[(size_t)gm * N + gn] = acc[mi][ni][j] + bias[gn];
        }
      }
    }
  }
}

// ---------------- flash attention core: one KV-tile step for one q-tile ----------------
__device__ __forceinline__ void tile_step(
    const uint16_t* __restrict__ Kc, const uint16_t* __restrict__ Vc, char* pw,
    bf16x8 qf0, bf16x8 qf1, f32x4 (&oacc)[4], float (&mj)[4], float (&lj)[4],
    int kt, int qt, int qbase, int w, int lg, int lr, int swzA, int swzB) {
  f32x4 sacc[4];
  __builtin_amdgcn_s_setprio(1);
  #pragma unroll
  for (int ni = 0; ni < 4; ++ni) {
    const char* kb = (const char*)Kc + (ni * 16 + lr) * 128;
    bf16x8 kf0 = *(const bf16x8_a*)(kb + swzA);
    bf16x8 kf1 = *(const bf16x8_a*)(kb + swzB);
    f32x4 s = {};
    s = __builtin_amdgcn_mfma_f32_16x16x32_bf16(qf0, kf0, s, 0, 0, 0);
    s = __builtin_amdgcn_mfma_f32_16x16x32_bf16(qf1, kf1, s, 0, 0, 0);
    sacc[ni] = s;
  }
  __builtin_amdgcn_s_setprio(0);
  float rowmax[4];
  if (kt == qt) {  // diagonal tile: causal mask
    rowmax[0] = rowmax[1] = rowmax[2] = rowmax[3] = -1e30f;
    int qg0 = qbase + w * 16 + lg * 4;
    #pragma unroll
    for (int ni = 0; ni < 4; ++ni) {
      int kg = kt * 64 + ni * 16 + lr;
      #pragma unroll
      for (int j = 0; j < 4; ++j) {
        float sv = (kg <= qg0 + j) ? sacc[ni][j] : -1e30f;
        sacc[ni][j] = sv;
        rowmax[j] = fmaxf(rowmax[j], sv);
      }
    }
  } else {
    #pragma unroll
    for (int j = 0; j < 4; ++j)
      rowmax[j] = fmaxf(fmaxf(sacc[0][j], sacc[1][j]), fmaxf(sacc[2][j], sacc[3][j]));
  }
  #pragma unroll
  for (int j = 0; j < 4; ++j)
    #pragma unroll
    for (int msk = 1; msk < 16; msk <<= 1)
      rowmax[j] = fmaxf(rowmax[j], __shfl_xor(rowmax[j], msk, 64));
  float g = fmaxf(fmaxf(rowmax[0] - mj[0], rowmax[1] - mj[1]),
                  fmaxf(rowmax[2] - mj[2], rowmax[3] - mj[3]));
  if (__any(g > 8.f)) {  // defer-max
    #pragma unroll
    for (int j = 0; j < 4; ++j) {
      float mn = fmaxf(mj[j], rowmax[j]);
      float c = exp2f(mj[j] - mn);
      mj[j] = mn;
      lj[j] *= c;
      #pragma unroll
      for (int nd = 0; nd < 4; ++nd) oacc[nd][j] *= c;
    }
  }
  // P = exp2(S - m), swizzled store to per-wave tile [16 q][64 k]
  #pragma unroll
  for (int ni = 0; ni < 4; ++ni) {
    int chunkbase = ni * 2 + (lr >> 3);
    int bofs = (lr & 7) * 2;
    #pragma unroll
    for (int j = 0; j < 4; ++j) {
      float p = exp2f(sacc[ni][j] - mj[j]);
      lj[j] += p;
      int q8 = (lg & 1) * 4 + j;
      *(__bf16*)(pw + (lg * 4 + j) * 128 + ((chunkbase ^ q8) << 4) + bofs) = (__bf16)p;
    }
  }
  bf16x8 pf0 = *(const bf16x8_a*)(pw + lr * 128 + swzA);
  bf16x8 pf1 = *(const bf16x8_a*)(pw + lr * 128 + swzB);
  __builtin_amdgcn_s_setprio(1);
  #pragma unroll
  for (int nd = 0; nd < 4; ++nd) {
    const char* vb = (const char*)Vc + (nd * 16 + lr) * 128;
    bf16x8 vf0 = *(const bf16x8_a*)(vb + swzA);
    bf16x8 vf1 = *(const bf16x8_a*)(vb + swzB);
    oacc[nd] = __builtin_amdgcn_mfma_f32_16x16x32_bf16(pf0, vf0, oacc[nd], 0, 0, 0);
    oacc[nd] = __builtin_amdgcn_mfma_f32_16x16x32_bf16(pf1, vf1, oacc[nd], 0, 0, 0);
  }
  __builtin_amdgcn_s_setprio(0);
}

__device__ __forceinline__ void store_o(
    uint16_t* __restrict__ O, f32x4 (&oacc)[4], float (&lj)[4],
    int qbase, int b, int h, int w, int lg, int lr) {
  #pragma unroll
  for (int j = 0; j < 4; ++j)
    #pragma unroll
    for (int msk = 1; msk < 16; msk <<= 1) lj[j] += __shfl_xor(lj[j], msk, 64);
  #pragma unroll
  for (int nd = 0; nd < 4; ++nd) {
    #pragma unroll
    for (int j = 0; j < 4; ++j) {
      int t = qbase + w * 16 + lg * 4 + j;
      float val = oacc[nd][j] / lj[j];
      O[((size_t)(b * TSEQ + t)) * CDIM + h * DH + nd * 16 + lr] = f2bu(val);
    }
  }
}

// ---------------- flash attention (causal): merged q-tile pair, dbuf K/V ----------------
// Q pre-scaled by 0.125*log2e -> softmax in exp2 domain.
// grid: id = qp*24 + bh  (24 == 0 mod 8 -> all blocks of a head share an XCD;
//                         longest blocks (qp=0) dispatch first)
__global__ __launch_bounds__(256) void attn_fwd(
    const uint16_t* __restrict__ Q, const uint16_t* __restrict__ K,
    const uint16_t* __restrict__ Vt, uint16_t* __restrict__ O) {
  int id = blockIdx.x;
  int qp = id / 24;
  int bh = id - qp * 24;
  int b = bh / NH, h = bh - b * NH;
  size_t base = (size_t)bh * TSEQ * DH;
  int tid = threadIdx.x, w = tid >> 6, l = tid & 63;
  int lg = l >> 4, lr = l & 15;
  __shared__ uint16_t Ks[2][64 * 64];
  __shared__ uint16_t Vs[2][64 * 64];
  __shared__ uint16_t Ps[4][16 * 64];
  char* pw = (char*)Ps[w];
  int srow = tid >> 3;
  int schunk = (tid & 7) ^ (srow & 7);
  const uint16_t* Kg0 = K + base + (size_t)srow * DH + schunk * 8;
  const uint16_t* Vg0 = Vt + base + (size_t)srow * TSEQ + schunk * 8;
  int swzA = (lg ^ (lr & 7)) << 4;
  int swzB = swzA ^ 64;

  int qtA = qp, qtB = 63 - qp;        // qtA < qtB always (qp <= 31)
  int qbaseA = qtA * 64, qbaseB = qtB * 64;
  int nt = qtB + 1;

  // prologue: stage tile 0 into buffer 0 (issue before Q loads so it flies early)
  {
    char* kd = (char*)Ks[0] + w * 1024;
    char* vd = (char*)Vs[0] + w * 1024;
    gload_lds16(Kg0, kd);
    gload_lds16(Kg0 + 32 * DH, kd + 4096);
    gload_lds16(Vg0, vd);
    gload_lds16(Vg0 + (size_t)32 * TSEQ, vd + 4096);
  }

  int qrowA = qbaseA + w * 16 + lr;
  int qrowB = qbaseB + w * 16 + lr;
  bf16x8 qA0 = *(const bf16x8_a*)(const void*)(Q + base + (size_t)qrowA * DH + lg * 8);
  bf16x8 qA1 = *(const bf16x8_a*)(const void*)(Q + base + (size_t)qrowA * DH + 32 + lg * 8);
  bf16x8 qB0 = *(const bf16x8_a*)(const void*)(Q + base + (size_t)qrowB * DH + lg * 8);
  bf16x8 qB1 = *(const bf16x8_a*)(const void*)(Q + base + (size_t)qrowB * DH + 32 + lg * 8);
  f32x4 oA[4] = {}, oB[4] = {};
  float mA[4] = {-1e30f, -1e30f, -1e30f, -1e30f};
  float lA[4] = {0.f, 0.f, 0.f, 0.f};
  float mB[4] = {-1e30f, -1e30f, -1e30f, -1e30f};
  float lB[4] = {0.f, 0.f, 0.f, 0.f};

  int buf = 0;
  for (int kt = 0; kt < nt; ++kt) {
    __syncthreads();  // stage for kt complete (vmcnt(0) drain), all waves done with buf^1
    if (kt + 1 < nt) {
      char* kd = (char*)Ks[buf ^ 1] + w * 1024;
      char* vd = (char*)Vs[buf ^ 1] + w * 1024;
      gload_lds16(Kg0 + (size_t)(kt + 1) * (64 * DH), kd);
      gload_lds16(Kg0 + (size_t)(kt + 1) * (64 * DH) + 32 * DH, kd + 4096);
      gload_lds16(Vg0 + (size_t)(kt + 1) * 64, vd);
      gload_lds16(Vg0 + (size_t)(kt + 1) * 64 + (size_t)32 * TSEQ, vd + 4096);
    }
    const uint16_t* Kc = Ks[buf];
    const uint16_t* Vc = Vs[buf];
    tile_step(Kc, Vc, pw, qB0, qB1, oB, mB, lB, kt, qtB, qbaseB, w, lg, lr, swzA, swzB);
    if (kt <= qtA)
      tile_step(Kc, Vc, pw, qA0, qA1, oA, mA, lA, kt, qtA, qbaseA, w, lg, lr, swzA, swzB);
    buf ^= 1;
  }
  store_o(O, oB, lB, qbaseB, b, h, w, lg, lr);
  store_o(O, oA, lA, qbaseA, b, h, w, lg, lr);
}

extern "C" void kernel_launch(void* const* d_in, const int* in_sizes, int n_in,
                              void* d_out, int out_size, void* d_ws, size_t ws_size,
                              hipStream_t stream) {
  const float* x    = (const float*)d_in[0];
  const float* Wqkv = (const float*)d_in[1];
  const float* bqkv = (const float*)d_in[2];
  const float* Wout = (const float*)d_in[3];
  const float* bout = (const float*)d_in[4];
  float* out = (float*)d_out;
  char* ws = (char*)d_ws;

  uint16_t* Xb    = (uint16_t*)(ws + 0);          // 8192*768*2   = 12,582,912
  uint16_t* Wqkvt = (uint16_t*)(ws + 12582912);   // 2304*768*2   =  3,538,944
  uint16_t* Woutt = (uint16_t*)(ws + 16121856);   // 768*768*2    =  1,179,648
  uint16_t* Qb    = (uint16_t*)(ws + 17301504);   // 12,582,912 (pre-scaled)
  uint16_t* Kb    = (uint16_t*)(ws + 29884416);   // 12,582,912
  uint16_t* Vtb   = (uint16_t*)(ws + 42467328);   // 12,582,912 (V^T [B,H,Dh,T])
  uint16_t* Ob    = (uint16_t*)(ws + 55050240);   // 12,582,912 (end 67,633,152)

  cast_f32_bf16<<<2048, 256, 0, stream>>>(x, Xb, (MROWS * CDIM) / 4);
  transpose_cast<<<dim3(24, 72), 256, 0, stream>>>(Wqkv, Wqkvt, 768, 2304);
  transpose_cast<<<dim3(24, 24), 256, 0, stream>>>(Wout, Woutt, 768, 768);
  gemm_bt<0><<<dim3(64, 18), 256, 0, stream>>>(Xb, Wqkvt, bqkv, Qb, Kb, Vtb, nullptr, 2304, 768);
  attn_fwd<<<768, 256, 0, stream>>>(Qb, Kb, Vtb, Ob);
  gemm_bt<1><<<dim3(64, 6), 256, 0, stream>>>(Ob, Woutt, bout, nullptr, nullptr, nullptr, out, 768, 768);
}

// Round 4
// 202.563 us; speedup vs baseline: 1.4769x; 1.4769x over previous
//
#include <hip/hip_runtime.h>
#include <hip/hip_bf16.h>
#include <cstdint>

#define NH 12
#define DH 64
#define TSEQ 4096
#define BATCH 2
#define CDIM 768
#define MROWS (BATCH*TSEQ)

typedef __bf16 bf16x8 __attribute__((ext_vector_type(8)));
typedef __bf16 bf16x4 __attribute__((ext_vector_type(4)));
typedef bf16x8 bf16x8_a __attribute__((may_alias));
typedef bf16x4 bf16x4_a __attribute__((may_alias));
typedef float f32x4 __attribute__((ext_vector_type(4)));

__device__ __forceinline__ uint16_t f2bu(float f) {
  uint32_t u = __float_as_uint(f);
  u += 0x7fffu + ((u >> 16) & 1u);
  return (uint16_t)(u >> 16);
}

__device__ __forceinline__ void gload_lds16(const void* g, void* l) {
  __builtin_amdgcn_global_load_lds(
      (const __attribute__((address_space(1))) void*)g,
      (__attribute__((address_space(3))) void*)l, 16, 0, 0);
}

// ---------------- cast fp32 -> bf16 (vectorized) ----------------
__global__ void cast_f32_bf16(const float* __restrict__ in, uint16_t* __restrict__ out, int n4) {
  int i = blockIdx.x * blockDim.x + threadIdx.x;
  int stride = gridDim.x * blockDim.x;
  for (; i < n4; i += stride) {
    float4 v = ((const float4*)in)[i];
    ushort4 o;
    o.x = f2bu(v.x); o.y = f2bu(v.y); o.z = f2bu(v.z); o.w = f2bu(v.w);
    ((ushort4*)out)[i] = o;
  }
}

// ---------------- transpose + cast: W[K][N] f32 -> Wt[N][K] bf16 ----------------
__global__ void transpose_cast(const float* __restrict__ w, uint16_t* __restrict__ wt, int K, int N) {
  __shared__ float tile[32][33];
  int kb = blockIdx.x * 32, nb = blockIdx.y * 32;
  int tx = threadIdx.x & 31, ty = threadIdx.x >> 5;
  #pragma unroll
  for (int r = ty; r < 32; r += 8) tile[r][tx] = w[(size_t)(kb + r) * N + nb + tx];
  __syncthreads();
  #pragma unroll
  for (int r = ty; r < 32; r += 8) wt[(size_t)(nb + r) * K + kb + tx] = f2bu(tile[tx][r]);
}

// ---------------- GEMM: C[M,N] = A[M,K](bf16) @ Bt[N,K]^T(bf16) + bias ----------------
// MODE 0: scatter Q (pre-scaled by 0.125*log2e) and K into [B,H,T,Dh]; V into V^T [B,H,Dh,T].
// MODE 1: write fp32 to outf [M,N].
template <int MODE>
__global__ __launch_bounds__(256) void gemm_bt(
    const uint16_t* __restrict__ A, const uint16_t* __restrict__ Bt,
    const float* __restrict__ bias,
    uint16_t* __restrict__ q, uint16_t* __restrict__ k, uint16_t* __restrict__ v,
    float* __restrict__ outf, int N, int K) {
  __shared__ uint16_t As[128 * 32];
  __shared__ uint16_t Bs[128 * 32];
  int tid = threadIdx.x;
  int w = tid >> 6, l = tid & 63;
  int lg = l >> 4, lr = l & 15;
  int mb = blockIdx.x * 128, nb = blockIdx.y * 128;
  int wr = (w >> 1) * 64, wc = (w & 1) * 64;
  f32x4 acc[4][4] = {};
  int srow = tid >> 2, scol = (tid & 3) * 8;
  const uint16_t* Ag = A + (size_t)(mb + srow) * K + scol;
  const uint16_t* Bg = Bt + (size_t)(nb + srow) * K + scol;
  char* AsB = (char*)As + (size_t)w * 1024;
  char* BsB = (char*)Bs + (size_t)w * 1024;
  size_t rowskip = (size_t)64 * K;
  for (int kb = 0; kb < K; kb += 32) {
    __syncthreads();
    gload_lds16(Ag + kb, AsB);
    gload_lds16(Ag + kb + rowskip, AsB + 4096);
    gload_lds16(Bg + kb, BsB);
    gload_lds16(Bg + kb + rowskip, BsB + 4096);
    __syncthreads();
    bf16x8 af[4], bfr[4];
    #pragma unroll
    for (int i = 0; i < 4; ++i)
      af[i] = *(const bf16x8_a*)(const void*)(As + (wr + i * 16 + lr) * 32 + lg * 8);
    #pragma unroll
    for (int i = 0; i < 4; ++i)
      bfr[i] = *(const bf16x8_a*)(const void*)(Bs + (wc + i * 16 + lr) * 32 + lg * 8);
    #pragma unroll
    for (int mi = 0; mi < 4; ++mi)
      #pragma unroll
      for (int ni = 0; ni < 4; ++ni)
        acc[mi][ni] = __builtin_amdgcn_mfma_f32_16x16x32_bf16(af[mi], bfr[ni], acc[mi][ni], 0, 0, 0);
  }
  #pragma unroll
  for (int mi = 0; mi < 4; ++mi) {
    #pragma unroll
    for (int ni = 0; ni < 4; ++ni) {
      if (MODE == 0) {
        int gm0 = mb + wr + mi * 16 + lg * 4;
        int gn = nb + wc + ni * 16 + lr;
        int which = gn / CDIM;
        int cc = gn - which * CDIM;
        int hh = cc >> 6, d = cc & 63;
        float bs = bias[gn];
        if (which == 2) {
          int b0 = gm0 >> 12, t0 = gm0 & 4095;
          ushort4 pk;
          pk.x = f2bu(acc[mi][ni][0] + bs);
          pk.y = f2bu(acc[mi][ni][1] + bs);
          pk.z = f2bu(acc[mi][ni][2] + bs);
          pk.w = f2bu(acc[mi][ni][3] + bs);
          *(ushort4*)&v[(((size_t)(b0 * NH + hh)) * DH + d) * TSEQ + t0] = pk;
        } else {
          uint16_t* dst = which ? k : q;
          float sc = which ? 1.0f : 0.1803368801111204f;  // 0.125 * log2(e)
          #pragma unroll
          for (int j = 0; j < 4; ++j) {
            int gm = gm0 + j;
            int bb = gm >> 12, t = gm & 4095;
            float val = (acc[mi][ni][j] + bs) * sc;
            dst[(((size_t)(bb * NH + hh)) * TSEQ + t) * DH + d] = f2bu(val);
          }
        }
      } else {
        #pragma unroll
        for (int j = 0; j < 4; ++j) {
          int gm = mb + wr + mi * 16 + lg * 4 + j;
          int gn = nb + wc + ni * 16 + lr;
          outf[(size_t)gm * N + gn] = acc[mi][ni][j] + bias[gn];
        }
      }
    }
  }
}

// ---------------- flash attention core (swapped QK^T: per-lane softmax row) ----------------
// S = mfma(K_frag, Q_frag): lane (lg,lr) holds S[q=lr][k=16ni+4lg+j].
// m,l are per-lane scalars for q-row lr (uniform across the 4 lg lanes after reduce).
__device__ __forceinline__ void tile_step_sw(
    const uint16_t* __restrict__ Kc, const uint16_t* __restrict__ Vc, char* pw,
    bf16x8 qf0, bf16x8 qf1, f32x4 (&oacc)[4], float& m, float& l,
    bool diag, int thr, int lane, int lg, int lr, int swzA, int swzB) {
  f32x4 sacc[4];
  __builtin_amdgcn_s_setprio(1);
  #pragma unroll
  for (int ni = 0; ni < 4; ++ni) {
    const char* kb = (const char*)Kc + (ni * 16 + lr) * 128;
    bf16x8 kf0 = *(const bf16x8_a*)(kb + swzA);
    bf16x8 kf1 = *(const bf16x8_a*)(kb + swzB);
    f32x4 s = {};
    s = __builtin_amdgcn_mfma_f32_16x16x32_bf16(kf0, qf0, s, 0, 0, 0);
    s = __builtin_amdgcn_mfma_f32_16x16x32_bf16(kf1, qf1, s, 0, 0, 0);
    sacc[ni] = s;
  }
  __builtin_amdgcn_s_setprio(0);
  if (diag) {  // causal mask: key_local = 16ni+4lg+j <= q - kb0  <=>  16ni+j <= thr
    #pragma unroll
    for (int ni = 0; ni < 4; ++ni)
      #pragma unroll
      for (int j = 0; j < 4; ++j)
        sacc[ni][j] = (16 * ni + j <= thr) ? sacc[ni][j] : -1e30f;
  }
  float r0 = fmaxf(fmaxf(sacc[0][0], sacc[0][1]), fmaxf(sacc[0][2], sacc[0][3]));
  float r1 = fmaxf(fmaxf(sacc[1][0], sacc[1][1]), fmaxf(sacc[1][2], sacc[1][3]));
  float r2 = fmaxf(fmaxf(sacc[2][0], sacc[2][1]), fmaxf(sacc[2][2], sacc[2][3]));
  float r3 = fmaxf(fmaxf(sacc[3][0], sacc[3][1]), fmaxf(sacc[3][2], sacc[3][3]));
  float rowmax = fmaxf(fmaxf(r0, r1), fmaxf(r2, r3));
  rowmax = fmaxf(rowmax, __shfl_xor(rowmax, 16, 64));
  rowmax = fmaxf(rowmax, __shfl_xor(rowmax, 32, 64));
  if (__any(rowmax - m > 8.f)) {  // defer-max: rescale only when max grows
    float mn = fmaxf(m, rowmax);
    float c = __builtin_amdgcn_exp2f(m - mn);
    m = mn;
    l *= c;
    #pragma unroll
    for (int j = 0; j < 4; ++j) {
      float cj = __shfl(c, (lane & 48) | (lg * 4 + j), 64);
      #pragma unroll
      for (int nd = 0; nd < 4; ++nd) oacc[nd][j] *= cj;
    }
  }
  // P = exp2(S - m); pack 4 consecutive-k bf16 -> one 8B store (swizzled)
  int pofs = (lg & 1) * 8;
  #pragma unroll
  for (int ni = 0; ni < 4; ++ni) {
    float p0 = __builtin_amdgcn_exp2f(sacc[ni][0] - m);
    float p1 = __builtin_amdgcn_exp2f(sacc[ni][1] - m);
    float p2 = __builtin_amdgcn_exp2f(sacc[ni][2] - m);
    float p3 = __builtin_amdgcn_exp2f(sacc[ni][3] - m);
    l += (p0 + p1) + (p2 + p3);
    bf16x4 pk;
    pk[0] = (__bf16)p0; pk[1] = (__bf16)p1; pk[2] = (__bf16)p2; pk[3] = (__bf16)p3;
    int chunk = (2 * ni + (lg >> 1)) ^ (lr & 7);
    *(bf16x4_a*)(pw + lr * 128 + chunk * 16 + pofs) = pk;
  }
  bf16x8 pf0 = *(const bf16x8_a*)(pw + lr * 128 + swzA);
  bf16x8 pf1 = *(const bf16x8_a*)(pw + lr * 128 + swzB);
  __builtin_amdgcn_s_setprio(1);
  #pragma unroll
  for (int nd = 0; nd < 4; ++nd) {
    const char* vb = (const char*)Vc + (nd * 16 + lr) * 128;
    bf16x8 vf0 = *(const bf16x8_a*)(vb + swzA);
    bf16x8 vf1 = *(const bf16x8_a*)(vb + swzB);
    oacc[nd] = __builtin_amdgcn_mfma_f32_16x16x32_bf16(pf0, vf0, oacc[nd], 0, 0, 0);
    oacc[nd] = __builtin_amdgcn_mfma_f32_16x16x32_bf16(pf1, vf1, oacc[nd], 0, 0, 0);
  }
  __builtin_amdgcn_s_setprio(0);
}

__device__ __forceinline__ void store_o_sw(
    uint16_t* __restrict__ O, f32x4 (&oacc)[4], float l,
    int qsb, int b, int h, int w, int lane, int lg, int lr) {
  l += __shfl_xor(l, 16, 64);
  l += __shfl_xor(l, 32, 64);
  float rinv = 1.0f / l;  // per-lane, for q-row lr
  #pragma unroll
  for (int j = 0; j < 4; ++j) {
    float rv = __shfl(rinv, (lane & 48) | (lg * 4 + j), 64);
    int t = qsb + w * 16 + lg * 4 + j;
    #pragma unroll
    for (int nd = 0; nd < 4; ++nd)
      O[((size_t)(b * TSEQ + t)) * CDIM + h * DH + nd * 16 + lr] = f2bu(oacc[nd][j] * rv);
  }
}

// ---------------- flash attention (causal): QBLK=128, one q-tile/block ----------------
// Q pre-scaled by 0.125*log2e -> softmax in exp2 domain.
// grid: id = qo*24 + bh, qt = 31-qo (longest first); bh inner -> same-head blocks share XCD.
__global__ __launch_bounds__(256) void attn_fwd(
    const uint16_t* __restrict__ Q, const uint16_t* __restrict__ K,
    const uint16_t* __restrict__ Vt, uint16_t* __restrict__ O) {
  int id = blockIdx.x;
  int qo = id / 24;
  int bh = id - qo * 24;
  int qt = 31 - qo;
  int b = bh / NH, h = bh - b * NH;
  size_t base = (size_t)bh * TSEQ * DH;
  int tid = threadIdx.x, w = tid >> 6, lane = tid & 63;
  int lg = lane >> 4, lr = lane & 15;
  __shared__ uint16_t Ks[64 * 64];
  __shared__ uint16_t Vs[64 * 64];
  __shared__ uint16_t Ps[4][16 * 64];
  char* pw = (char*)Ps[w];
  int srow = tid >> 3;
  int schunk = (tid & 7) ^ (srow & 7);
  const uint16_t* Kg0 = K + base + (size_t)srow * DH + schunk * 8;
  const uint16_t* Vg0 = Vt + base + (size_t)srow * TSEQ + schunk * 8;
  char* KsB = (char*)Ks + w * 1024;
  char* VsB = (char*)Vs + w * 1024;
  int swzA = (lg ^ (lr & 7)) << 4;
  int swzB = swzA ^ 64;

  int q0 = qt * 128;          // q-sub A rows q0..q0+63
  int q1 = q0 + 64;           // q-sub B rows q1..q1+63
  int qgA = q0 + w * 16 + lr; // this lane's absolute q-row (sub A)
  int qgB = q1 + w * 16 + lr;
  bf16x8 qA0 = *(const bf16x8_a*)(const void*)(Q + base + (size_t)qgA * DH + lg * 8);
  bf16x8 qA1 = *(const bf16x8_a*)(const void*)(Q + base + (size_t)qgA * DH + 32 + lg * 8);
  bf16x8 qB0 = *(const bf16x8_a*)(const void*)(Q + base + (size_t)qgB * DH + lg * 8);
  bf16x8 qB1 = *(const bf16x8_a*)(const void*)(Q + base + (size_t)qgB * DH + 32 + lg * 8);
  f32x4 oA[4] = {}, oB[4] = {};
  float mA = -1e30f, lA = 0.f, mB = -1e30f, lB = 0.f;

  int nt = 2 * qt + 2;
  int lg4 = lg * 4;
  for (int kt = 0; kt < nt; ++kt) {
    __syncthreads();  // all waves done reading Ks/Vs from previous iter
    gload_lds16(Kg0 + (size_t)kt * (64 * DH), KsB);
    gload_lds16(Kg0 + (size_t)kt * (64 * DH) + 32 * DH, KsB + 4096);
    gload_lds16(Vg0 + (size_t)kt * 64, VsB);
    gload_lds16(Vg0 + (size_t)kt * 64 + (size_t)32 * TSEQ, VsB + 4096);
    __syncthreads();  // stage complete (vmcnt drain)
    int kb0 = kt * 64;
    if (kt <= 2 * qt)
      tile_step_sw(Ks, Vs, pw, qA0, qA1, oA, mA, lA,
                   kt == 2 * qt, qgA - kb0 - lg4, lane, lg, lr, swzA, swzB);
    tile_step_sw(Ks, Vs, pw, qB0, qB1, oB, mB, lB,
                 kt == 2 * qt + 1, qgB - kb0 - lg4, lane, lg, lr, swzA, swzB);
  }
  store_o_sw(O, oA, lA, q0, b, h, w, lane, lg, lr);
  store_o_sw(O, oB, lB, q1, b, h, w, lane, lg, lr);
}

extern "C" void kernel_launch(void* const* d_in, const int* in_sizes, int n_in,
                              void* d_out, int out_size, void* d_ws, size_t ws_size,
                              hipStream_t stream) {
  const float* x    = (const float*)d_in[0];
  const float* Wqkv = (const float*)d_in[1];
  const float* bqkv = (const float*)d_in[2];
  const float* Wout = (const float*)d_in[3];
  const float* bout = (const float*)d_in[4];
  float* out = (float*)d_out;
  char* ws = (char*)d_ws;

  uint16_t* Xb    = (uint16_t*)(ws + 0);          // 8192*768*2   = 12,582,912
  uint16_t* Wqkvt = (uint16_t*)(ws + 12582912);   // 2304*768*2   =  3,538,944
  uint16_t* Woutt = (uint16_t*)(ws + 16121856);   // 768*768*2    =  1,179,648
  uint16_t* Qb    = (uint16_t*)(ws + 17301504);   // 12,582,912 (pre-scaled)
  uint16_t* Kb    = (uint16_t*)(ws + 29884416);   // 12,582,912
  uint16_t* Vtb   = (uint16_t*)(ws + 42467328);   // 12,582,912 (V^T [B,H,Dh,T])
  uint16_t* Ob    = (uint16_t*)(ws + 55050240);   // 12,582,912 (end 67,633,152)

  cast_f32_bf16<<<2048, 256, 0, stream>>>(x, Xb, (MROWS * CDIM) / 4);
  transpose_cast<<<dim3(24, 72), 256, 0, stream>>>(Wqkv, Wqkvt, 768, 2304);
  transpose_cast<<<dim3(24, 24), 256, 0, stream>>>(Wout, Woutt, 768, 768);
  gemm_bt<0><<<dim3(64, 18), 256, 0, stream>>>(Xb, Wqkvt, bqkv, Qb, Kb, Vtb, nullptr, 2304, 768);
  attn_fwd<<<768, 256, 0, stream>>>(Qb, Kb, Vtb, Ob);
  gemm_bt<1><<<dim3(64, 6), 256, 0, stream>>>(Ob, Woutt, bout, nullptr, nullptr, nullptr, out, 768, 768);
}